// Round 1
// baseline (513.872 us; speedup 1.0000x reference)
//
#include <hip/hip_runtime.h>

// Problem: out[b,n] = sum_{c,hw} x[b,c,hw]*W_s[n,hw]*W_d[n,c] + W_b[n]
// B=32, C=256, H=W=56 (HW=3136), N=1024.
// GEMM view: A = x as (M=8192, K=3136) row-major; B = W_s as (N=1024, K=3136)
// row-major (i.e. B^T layout); fused epilogue contracts c with W_d.

#define K_DIM 3136
#define N_DIM 1024
#define C_DIM 256
#define B_DIM 32
#define M_DIM (B_DIM * C_DIM)   // 8192
#define BK 64
#define LDS_STRIDE 72           // 64 + 8 pad (bf16 elems); row stride 144 B

typedef __attribute__((ext_vector_type(8))) short short8v;  // 8 bf16 = 4 VGPR
typedef __attribute__((ext_vector_type(4))) short short4v;  // 8 B ds_write_b64
typedef __attribute__((ext_vector_type(4))) float f32x4;

// round-to-nearest-even fp32 -> bf16
__device__ __forceinline__ short f2bf(float f) {
  union { float f; unsigned u; } v; v.f = f;
  unsigned r = v.u + 0x7FFFu + ((v.u >> 16) & 1u);
  return (short)(r >> 16);
}

__global__ __launch_bounds__(256) void bias_init(const float* __restrict__ Wb,
                                                 float* __restrict__ out) {
  int i = blockIdx.x * 256 + threadIdx.x;
  out[i] = Wb[i & (N_DIM - 1)];
}

__global__ __launch_bounds__(256, 2) void gemm_fused(
    const float* __restrict__ x, const float* __restrict__ Ws,
    const float* __restrict__ Wd, float* __restrict__ out) {
  __shared__ __align__(16) short As[128 * LDS_STRIDE];
  __shared__ __align__(16) short Bs[128 * LDS_STRIDE];

  const int bid = blockIdx.x;
  const int mt = bid & 63;   // A-tile id; XCD = bid%8 = mt%8 -> A-tile pinned to XCD
  const int nt = bid >> 6;
  const int m0 = mt * 128;
  const int n0 = nt * 128;

  const int t = threadIdx.x;
  const int wave = t >> 6;
  const int lane = t & 63;
  const int r = lane & 15;   // MFMA row/col-in-frag lane index
  const int q = lane >> 4;   // quad index
  const int wm = wave >> 1;  // wave grid 2x2: wm = M half, wn = N half
  const int wn = wave & 1;

  const float4* Ag = (const float4*)(x + (size_t)m0 * K_DIM);
  const float4* Bg = (const float4*)(Ws + (size_t)n0 * K_DIM);

  // staging decomposition: thread t, rep i handles flat float4 f = t + 256*i
  const int row_base = t >> 4;   // + 16*i
  const int k4 = t & 15;         // float4 index within the 64-wide K tile

  f32x4 acc[4][4];
#pragma unroll
  for (int i = 0; i < 4; ++i)
#pragma unroll
    for (int j = 0; j < 4; ++j) acc[i][j] = (f32x4)0.0f;

  for (int kt = 0; kt < K_DIM / BK; ++kt) {
    const int kq0 = kt * (BK / 4);   // float4 offset of this K tile
    __syncthreads();                  // LDS reuse fence (prev reads done)

    // ---- stage A: 128x64 fp32 -> bf16 LDS ----
#pragma unroll
    for (int i = 0; i < 8; ++i) {
      const int row = row_base + 16 * i;
      float4 v = Ag[(size_t)row * (K_DIM / 4) + kq0 + k4];
      short4v s;
      s.x = f2bf(v.x); s.y = f2bf(v.y); s.z = f2bf(v.z); s.w = f2bf(v.w);
      *(short4v*)&As[row * LDS_STRIDE + k4 * 4] = s;
    }
    // ---- stage B: 128x64 fp32 -> bf16 LDS ----
#pragma unroll
    for (int i = 0; i < 8; ++i) {
      const int row = row_base + 16 * i;
      float4 v = Bg[(size_t)row * (K_DIM / 4) + kq0 + k4];
      short4v s;
      s.x = f2bf(v.x); s.y = f2bf(v.y); s.z = f2bf(v.z); s.w = f2bf(v.w);
      *(short4v*)&Bs[row * LDS_STRIDE + k4 * 4] = s;
    }
    __syncthreads();

    // ---- MFMA over the 64-deep K tile (2 k-steps of 32) ----
#pragma unroll
    for (int ks = 0; ks < 2; ++ks) {
      short8v a[4], b[4];
#pragma unroll
      for (int i = 0; i < 4; ++i) {
        const int m_l = 64 * wm + 16 * i + r;
        a[i] = *(const short8v*)&As[m_l * LDS_STRIDE + ks * 32 + q * 8];
      }
#pragma unroll
      for (int j = 0; j < 4; ++j) {
        const int n_l = 64 * wn + 16 * j + r;
        b[j] = *(const short8v*)&Bs[n_l * LDS_STRIDE + ks * 32 + q * 8];
      }
#pragma unroll
      for (int i = 0; i < 4; ++i)
#pragma unroll
        for (int j = 0; j < 4; ++j)
          acc[i][j] =
              __builtin_amdgcn_mfma_f32_16x16x32_bf16(a[i], b[j], acc[i][j], 0, 0, 0);
    }
  }

  // ---- fused epilogue: out[b, n] += sum_c acc[c_l, n_l] * W_d[n, c] ----
  // C/D frag layout: col = lane&15 (n), row = q*4 + reg (m/c).
  const int b_idx = mt >> 1;          // 2 M-tiles per batch image
  const int c0 = (mt & 1) * 128;      // c offset of this M-tile
#pragma unroll
  for (int j = 0; j < 4; ++j) {
    const int n_g = n0 + 64 * wn + 16 * j + r;   // global n
    float p = 0.0f;
#pragma unroll
    for (int i = 0; i < 4; ++i) {
      const int c_l = c0 + 64 * wm + 16 * i + 4 * q;  // global c of acc rows
      const float4 wd = *(const float4*)(Wd + (size_t)n_g * C_DIM + c_l);
      p += acc[i][j].x * wd.x + acc[i][j].y * wd.y +
           acc[i][j].z * wd.z + acc[i][j].w * wd.w;
    }
    // reduce over quads (each quad holds a different 4-row slice of c)
    p += __shfl_xor(p, 16, 64);
    p += __shfl_xor(p, 32, 64);
    if (q == 0)
      atomicAdd(&out[(size_t)b_idx * N_DIM + n_g], p);
  }
}

extern "C" void kernel_launch(void* const* d_in, const int* in_sizes, int n_in,
                              void* d_out, int out_size, void* d_ws, size_t ws_size,
                              hipStream_t stream) {
  const float* x  = (const float*)d_in[0];
  const float* Ws = (const float*)d_in[1];
  const float* Wd = (const float*)d_in[2];
  const float* Wb = (const float*)d_in[3];
  float* out = (float*)d_out;

  bias_init<<<dim3((B_DIM * N_DIM) / 256), dim3(256), 0, stream>>>(Wb, out);
  gemm_fused<<<dim3((M_DIM / 128) * (N_DIM / 128)), dim3(256), 0, stream>>>(
      x, Ws, Wd, out);
}

// Round 2
// 235.279 us; speedup vs baseline: 2.1841x; 2.1841x over previous
//
#include <hip/hip_runtime.h>
#include <stdint.h>

// out[b,n] = sum_{c,hw} x[b,c,hw]*W_s[n,hw]*W_d[n,c] + W_b[n]
// GEMM: A = x (M=8192, K=3136), B = W_s (N=1024, K=3136), fused c-contraction.
// R1: bf16 pre-convert into d_ws + m97-style global_load_lds(16B) K-loop,
//     XOR-swizzled LDS slots (no padding allowed with global_load_lds),
//     K-split x2 -> 1024 blocks (4/CU co-resident).

#define K_DIM 3136
#define N_DIM 1024
#define C_DIM 256
#define B_DIM 32
#define M_DIM 8192
#define X_ELEMS (M_DIM * K_DIM)   // 25690112
#define WS_ELEMS (N_DIM * K_DIM)  // 3211264

typedef __attribute__((ext_vector_type(8))) short short8v;  // 8 bf16
typedef __attribute__((ext_vector_type(4))) short short4v;
typedef __attribute__((ext_vector_type(4))) float f32x4;

__device__ __forceinline__ short f2bf(float f) {
  union { float f; unsigned u; } v; v.f = f;
  unsigned r = v.u + 0x7FFFu + ((v.u >> 16) & 1u);
  return (short)(r >> 16);
}

// 16B-per-lane async global->LDS. LDS dest = wave-uniform base + lane*16.
__device__ __forceinline__ void async16(const void* g, void* l) {
  __builtin_amdgcn_global_load_lds(
      (const __attribute__((address_space(1))) unsigned int*)g,
      (__attribute__((address_space(3))) unsigned int*)l, 16, 0, 0);
}

__global__ __launch_bounds__(256) void bias_init(const float* __restrict__ Wb,
                                                 float* __restrict__ out) {
  int i = blockIdx.x * 256 + threadIdx.x;
  out[i] = Wb[i & (N_DIM - 1)];
}

// fp32 -> bf16 for x (blocks [0, 25088)) and W_s (blocks [25088, 28224)).
__global__ __launch_bounds__(256) void convert_bf16(const float* __restrict__ x,
                                                    const float* __restrict__ Ws,
                                                    short* __restrict__ dst) {
  const int xblocks = X_ELEMS / 1024;  // 25088
  int bid = blockIdx.x;
  const float* src;
  short* d;
  size_t base;
  if (bid < xblocks) {
    src = x; d = dst; base = (size_t)bid * 1024;
  } else {
    src = Ws; d = dst + X_ELEMS; base = (size_t)(bid - xblocks) * 1024;
  }
  size_t i = base + threadIdx.x * 4;
  float4 v = *(const float4*)(src + i);
  short4v s;
  s.x = f2bf(v.x); s.y = f2bf(v.y); s.z = f2bf(v.z); s.w = f2bf(v.w);
  *(short4v*)(d + i) = s;
}

// LDS layout: tile = 128 rows x 8 chunks (chunk = 8 bf16 = 16 B), unpadded.
// slot(row, cs) at byte (row*8 + cs)*16 holds global chunk k8 = cs ^ (row&7).
// Fragment read of (row, k8) -> byte row*128 + (k8 ^ (row&7))*16: the 16
// lanes sharing a quad spread over all 8 bank-groups -> 2 lanes/bank (free).
__global__ __launch_bounds__(256) void gemm_fused(
    const short* __restrict__ Abf, const short* __restrict__ Bbf,
    const float* __restrict__ Wd, float* __restrict__ out) {
  __shared__ __align__(16) short As[128 * 64];  // 16 KB
  __shared__ __align__(16) short Bs[128 * 64];  // 16 KB

  const int bid = blockIdx.x;
  const int mt = bid & 63;          // bid%8 == mt%8 -> A-tile pinned to XCD
  const int nt = (bid >> 6) & 7;
  const int z = bid >> 9;           // K-split half
  const int kt0 = z * 25;
  const int ktn = z ? 24 : 25;      // 25 + 24 = 49 K-tiles of 64

  const int t = threadIdx.x;
  const int lane = t & 63;
  const int wv = t >> 6;
  const int r = lane & 15;
  const int q = lane >> 4;
  const int wm = wv >> 1, wn = wv & 1;  // 2x2 wave grid over 128x128 tile

  // staging: wave wv, instr p covers rows [wv*32 + p*8, +8); lane -> (rr, cs)
  const int rr = lane >> 3;         // row within 8-row group
  const int k8 = (lane & 7) ^ rr;   // swizzled global chunk for this slot
  const short* Aw = Abf + (size_t)(mt * 128 + wv * 32 + rr) * K_DIM + k8 * 8 + kt0 * 64;
  const short* Bw = Bbf + (size_t)(nt * 128 + wv * 32 + rr) * K_DIM + k8 * 8 + kt0 * 64;
  char* AsB = (char*)As + wv * 4096;
  char* BsB = (char*)Bs + wv * 4096;

  f32x4 acc[4][4];
#pragma unroll
  for (int i = 0; i < 4; ++i)
#pragma unroll
    for (int j = 0; j < 4; ++j) acc[i][j] = (f32x4)0.0f;

  for (int kt = 0; kt < ktn; ++kt) {
    __syncthreads();  // prev iteration's LDS reads done
#pragma unroll
    for (int p = 0; p < 4; ++p) {
      async16(Aw + (size_t)p * 8 * K_DIM + kt * 64, AsB + p * 1024);
      async16(Bw + (size_t)p * 8 * K_DIM + kt * 64, BsB + p * 1024);
    }
    __syncthreads();  // vmcnt(0) drain: DMA complete across all waves

#pragma unroll
    for (int ks = 0; ks < 2; ++ks) {
      const int xo = ((ks * 4 + q) ^ (r & 7)) * 16;
      short8v a[4], b[4];
#pragma unroll
      for (int i = 0; i < 4; ++i)
        a[i] = *(const short8v*)((const char*)As + (64 * wm + 16 * i + r) * 128 + xo);
#pragma unroll
      for (int j = 0; j < 4; ++j)
        b[j] = *(const short8v*)((const char*)Bs + (64 * wn + 16 * j + r) * 128 + xo);
#pragma unroll
      for (int i = 0; i < 4; ++i)
#pragma unroll
        for (int j = 0; j < 4; ++j)
          acc[i][j] = __builtin_amdgcn_mfma_f32_16x16x32_bf16(a[i], b[j],
                                                              acc[i][j], 0, 0, 0);
    }
  }

  // epilogue: out[b, n] += sum_c acc * W_d[n, c]; C/D: col=lane&15, row=q*4+reg
  const int b_idx = mt >> 1;
  const int c0 = (mt & 1) * 128;
  const int n0 = nt * 128;
#pragma unroll
  for (int j = 0; j < 4; ++j) {
    const int n_g = n0 + 64 * wn + 16 * j + r;
    float p = 0.0f;
#pragma unroll
    for (int i = 0; i < 4; ++i) {
      const int c_l = c0 + 64 * wm + 16 * i + 4 * q;
      const float4 wd = *(const float4*)(Wd + (size_t)n_g * C_DIM + c_l);
      p += acc[i][j].x * wd.x + acc[i][j].y * wd.y + acc[i][j].z * wd.z +
           acc[i][j].w * wd.w;
    }
    p += __shfl_xor(p, 16, 64);
    p += __shfl_xor(p, 32, 64);
    if (q == 0) atomicAdd(&out[(size_t)b_idx * N_DIM + n_g], p);
  }
}

extern "C" void kernel_launch(void* const* d_in, const int* in_sizes, int n_in,
                              void* d_out, int out_size, void* d_ws, size_t ws_size,
                              hipStream_t stream) {
  const float* x = (const float*)d_in[0];
  const float* Ws = (const float*)d_in[1];
  const float* Wd = (const float*)d_in[2];
  const float* Wb = (const float*)d_in[3];
  float* out = (float*)d_out;
  short* xbf = (short*)d_ws;  // [X_ELEMS] bf16 x, then [WS_ELEMS] bf16 W_s

  bias_init<<<dim3((B_DIM * N_DIM) / 256), dim3(256), 0, stream>>>(Wb, out);
  convert_bf16<<<dim3((X_ELEMS + WS_ELEMS) / 1024), dim3(256), 0, stream>>>(x, Ws, xbf);
  gemm_fused<<<dim3(64 * 8 * 2), dim3(256), 0, stream>>>(xbf, xbf + X_ELEMS, Wd, out);
}

// Round 4
// 222.993 us; speedup vs baseline: 2.3044x; 1.0551x over previous
//
#include <hip/hip_runtime.h>
#include <stdint.h>

// out[b,n] = sum_{c,hw} x[b,c,hw]*W_s[n,hw]*W_d[n,c] + W_b[n]
// GEMM: A = x (M=8192, K=3136), B = W_s (N=1024, K=3136), fused c-contraction.
// R3: same as R2 (K-split x4 -> 5 resident blocks/CU; convert 8 elem/thread,
//     nontemporal loads) with the nontemporal builtin applied to a native
//     ext_vector type (HIP_vector_type<float,4> is rejected by the builtin).

#define K_DIM 3136
#define N_DIM 1024
#define C_DIM 256
#define B_DIM 32
#define M_DIM 8192
#define X_ELEMS (M_DIM * K_DIM)   // 25690112
#define WS_ELEMS (N_DIM * K_DIM)  // 3211264

typedef __attribute__((ext_vector_type(8))) short short8v;  // 8 bf16
typedef __attribute__((ext_vector_type(4))) short short4v;
typedef __attribute__((ext_vector_type(4))) float f32x4;

__device__ __forceinline__ short f2bf(float f) {
  union { float f; unsigned u; } v; v.f = f;
  unsigned r = v.u + 0x7FFFu + ((v.u >> 16) & 1u);
  return (short)(r >> 16);
}

// 16B-per-lane async global->LDS. LDS dest = wave-uniform base + lane*16.
__device__ __forceinline__ void async16(const void* g, void* l) {
  __builtin_amdgcn_global_load_lds(
      (const __attribute__((address_space(1))) unsigned int*)g,
      (__attribute__((address_space(3))) unsigned int*)l, 16, 0, 0);
}

__global__ __launch_bounds__(256) void bias_init(const float* __restrict__ Wb,
                                                 float* __restrict__ out) {
  int i = blockIdx.x * 256 + threadIdx.x;
  out[i] = Wb[i & (N_DIM - 1)];
}

// fp32 -> bf16, 8 elems/thread. Blocks [0,12544) = x, [12544,14112) = W_s.
__global__ __launch_bounds__(256) void convert_bf16(const float* __restrict__ x,
                                                    const float* __restrict__ Ws,
                                                    short* __restrict__ dst) {
  const int xblocks = X_ELEMS / 2048;  // 12544
  int bid = blockIdx.x;
  const float* src;
  short* d;
  size_t base;
  if (bid < xblocks) {
    src = x; d = dst; base = (size_t)bid * 2048;
  } else {
    src = Ws; d = dst + X_ELEMS; base = (size_t)(bid - xblocks) * 2048;
  }
  size_t i = base + threadIdx.x * 8;
  f32x4 v0 = __builtin_nontemporal_load((const f32x4*)(src + i));
  f32x4 v1 = __builtin_nontemporal_load((const f32x4*)(src + i) + 1);
  short8v s;
  s[0] = f2bf(v0.x); s[1] = f2bf(v0.y); s[2] = f2bf(v0.z); s[3] = f2bf(v0.w);
  s[4] = f2bf(v1.x); s[5] = f2bf(v1.y); s[6] = f2bf(v1.z); s[7] = f2bf(v1.w);
  *(short8v*)(d + i) = s;
}

// LDS: tile = 128 rows x 8 chunks (chunk = 8 bf16 = 16 B), unpadded (DMA dest).
// slot(row, cs) holds global chunk k8 = cs ^ (row&7); frag reads XOR back ->
// 2 lanes/bank, conflict-free (verified R1: SQ_LDS_BANK_CONFLICT = 0).
__global__ __launch_bounds__(256) void gemm_fused(
    const short* __restrict__ Abf, const short* __restrict__ Bbf,
    const float* __restrict__ Wd, float* __restrict__ out) {
  __shared__ __align__(16) short As[128 * 64];  // 16 KB
  __shared__ __align__(16) short Bs[128 * 64];  // 16 KB

  const int bid = blockIdx.x;
  const int mt = bid & 63;          // bid%8 == mt%8 -> A-tile pinned to XCD
  const int nt = (bid >> 6) & 7;
  const int z = bid >> 9;           // K-split quarter: 49 = 13+12+12+12
  const int kt0 = (z == 0) ? 0 : (13 + (z - 1) * 12);
  const int ktn = (z == 0) ? 13 : 12;

  const int t = threadIdx.x;
  const int lane = t & 63;
  const int wv = t >> 6;
  const int r = lane & 15;
  const int q = lane >> 4;
  const int wm = wv >> 1, wn = wv & 1;  // 2x2 wave grid over 128x128 tile

  // staging: wave wv, instr p covers rows [wv*32 + p*8, +8); lane -> (rr, cs)
  const int rr = lane >> 3;         // row within 8-row group
  const int k8 = (lane & 7) ^ rr;   // swizzled global chunk for this slot
  const short* Aw = Abf + (size_t)(mt * 128 + wv * 32 + rr) * K_DIM + k8 * 8 + kt0 * 64;
  const short* Bw = Bbf + (size_t)(nt * 128 + wv * 32 + rr) * K_DIM + k8 * 8 + kt0 * 64;
  char* AsB = (char*)As + wv * 4096;
  char* BsB = (char*)Bs + wv * 4096;

  f32x4 acc[4][4];
#pragma unroll
  for (int i = 0; i < 4; ++i)
#pragma unroll
    for (int j = 0; j < 4; ++j) acc[i][j] = (f32x4)0.0f;

  for (int kt = 0; kt < ktn; ++kt) {
    __syncthreads();  // prev iteration's LDS reads done
#pragma unroll
    for (int p = 0; p < 4; ++p) {
      async16(Aw + (size_t)p * 8 * K_DIM + kt * 64, AsB + p * 1024);
      async16(Bw + (size_t)p * 8 * K_DIM + kt * 64, BsB + p * 1024);
    }
    __syncthreads();  // vmcnt(0) drain: DMA complete across all waves

#pragma unroll
    for (int ks = 0; ks < 2; ++ks) {
      const int xo = ((ks * 4 + q) ^ (r & 7)) * 16;
      short8v a[4], b[4];
#pragma unroll
      for (int i = 0; i < 4; ++i)
        a[i] = *(const short8v*)((const char*)As + (64 * wm + 16 * i + r) * 128 + xo);
#pragma unroll
      for (int j = 0; j < 4; ++j)
        b[j] = *(const short8v*)((const char*)Bs + (64 * wn + 16 * j + r) * 128 + xo);
#pragma unroll
      for (int i = 0; i < 4; ++i)
#pragma unroll
        for (int j = 0; j < 4; ++j)
          acc[i][j] = __builtin_amdgcn_mfma_f32_16x16x32_bf16(a[i], b[j],
                                                              acc[i][j], 0, 0, 0);
    }
  }

  // epilogue: out[b, n] += sum_c acc * W_d[n, c]; C/D: col=lane&15, row=q*4+reg
  const int b_idx = mt >> 1;
  const int c0 = (mt & 1) * 128;
  const int n0 = nt * 128;
#pragma unroll
  for (int j = 0; j < 4; ++j) {
    const int n_g = n0 + 64 * wn + 16 * j + r;
    float p = 0.0f;
#pragma unroll
    for (int i = 0; i < 4; ++i) {
      const int c_l = c0 + 64 * wm + 16 * i + 4 * q;
      const float4 wd = *(const float4*)(Wd + (size_t)n_g * C_DIM + c_l);
      p += acc[i][j].x * wd.x + acc[i][j].y * wd.y + acc[i][j].z * wd.z +
           acc[i][j].w * wd.w;
    }
    p += __shfl_xor(p, 16, 64);
    p += __shfl_xor(p, 32, 64);
    if (q == 0) atomicAdd(&out[(size_t)b_idx * N_DIM + n_g], p);
  }
}

extern "C" void kernel_launch(void* const* d_in, const int* in_sizes, int n_in,
                              void* d_out, int out_size, void* d_ws, size_t ws_size,
                              hipStream_t stream) {
  const float* x = (const float*)d_in[0];
  const float* Ws = (const float*)d_in[1];
  const float* Wd = (const float*)d_in[2];
  const float* Wb = (const float*)d_in[3];
  float* out = (float*)d_out;
  short* xbf = (short*)d_ws;  // [X_ELEMS] bf16 x, then [WS_ELEMS] bf16 W_s

  bias_init<<<dim3((B_DIM * N_DIM) / 256), dim3(256), 0, stream>>>(Wb, out);
  convert_bf16<<<dim3((X_ELEMS + WS_ELEMS) / 2048), dim3(256), 0, stream>>>(x, Ws, xbf);
  gemm_fused<<<dim3(64 * 8 * 4), dim3(256), 0, stream>>>(xbf, xbf + X_ELEMS, Wd, out);
}

// Round 5
// 211.967 us; speedup vs baseline: 2.4243x; 1.0520x over previous
//
#include <hip/hip_runtime.h>
#include <stdint.h>

// out[b,n] = sum_{c,hw} x[b,c,hw]*W_s[n,hw]*W_d[n,c] + W_b[n]
// GEMM: A = x (M=8192, K=3136), B = W_s (N=1024, K=3136), fused c-contraction.
// R4: __launch_bounds__(256,4) to force <=128 regs/wave (arch+acc unified on
//     gfx950) -> 4 resident blocks/CU instead of 3 (R3: 84 arch + 64 acc =
//     148 -> 3 waves/SIMD, occupancy-capped). Bias init merged into convert.

#define K_DIM 3136
#define N_DIM 1024
#define C_DIM 256
#define B_DIM 32
#define M_DIM 8192
#define X_ELEMS (M_DIM * K_DIM)   // 25690112
#define WS_ELEMS (N_DIM * K_DIM)  // 3211264

typedef __attribute__((ext_vector_type(8))) short short8v;  // 8 bf16
typedef __attribute__((ext_vector_type(4))) short short4v;
typedef __attribute__((ext_vector_type(4))) float f32x4;

__device__ __forceinline__ short f2bf(float f) {
  union { float f; unsigned u; } v; v.f = f;
  unsigned r = v.u + 0x7FFFu + ((v.u >> 16) & 1u);
  return (short)(r >> 16);
}

// 16B-per-lane async global->LDS. LDS dest = wave-uniform base + lane*16.
__device__ __forceinline__ void async16(const void* g, void* l) {
  __builtin_amdgcn_global_load_lds(
      (const __attribute__((address_space(1))) unsigned int*)g,
      (__attribute__((address_space(3))) unsigned int*)l, 16, 0, 0);
}

// fp32 -> bf16 for x and W_s, plus bias broadcast into out (last 128 blocks).
#define XBLK (X_ELEMS / 2048)                 // 12544
#define CVBLK ((X_ELEMS + WS_ELEMS) / 2048)   // 14112
__global__ __launch_bounds__(256) void convert_bf16_bias(
    const float* __restrict__ x, const float* __restrict__ Ws,
    const float* __restrict__ Wb, short* __restrict__ dst,
    float* __restrict__ out) {
  int bid = blockIdx.x;
  if (bid >= CVBLK) {  // bias: 32768 out elems / 256 = 128 blocks
    int i = (bid - CVBLK) * 256 + threadIdx.x;
    out[i] = Wb[i & (N_DIM - 1)];
    return;
  }
  const float* src;
  short* d;
  size_t base;
  if (bid < XBLK) {
    src = x; d = dst; base = (size_t)bid * 2048;
  } else {
    src = Ws; d = dst + X_ELEMS; base = (size_t)(bid - XBLK) * 2048;
  }
  size_t i = base + threadIdx.x * 8;
  f32x4 v0 = __builtin_nontemporal_load((const f32x4*)(src + i));
  f32x4 v1 = __builtin_nontemporal_load((const f32x4*)(src + i) + 1);
  short8v s;
  s[0] = f2bf(v0.x); s[1] = f2bf(v0.y); s[2] = f2bf(v0.z); s[3] = f2bf(v0.w);
  s[4] = f2bf(v1.x); s[5] = f2bf(v1.y); s[6] = f2bf(v1.z); s[7] = f2bf(v1.w);
  *(short8v*)(d + i) = s;
}

// LDS: tile = 128 rows x 8 chunks (chunk = 8 bf16 = 16 B), unpadded (DMA dest).
// slot(row, cs) holds global chunk k8 = cs ^ (row&7); frag reads XOR back ->
// conflict-free (verified R1/R3: SQ_LDS_BANK_CONFLICT = 0).
__global__ __launch_bounds__(256, 4) void gemm_fused(
    const short* __restrict__ Abf, const short* __restrict__ Bbf,
    const float* __restrict__ Wd, float* __restrict__ out) {
  __shared__ __align__(16) short As[128 * 64];  // 16 KB
  __shared__ __align__(16) short Bs[128 * 64];  // 16 KB

  const int bid = blockIdx.x;
  const int mt = bid & 63;          // bid%8 == mt%8 -> A-tile pinned to XCD
  const int nt = (bid >> 6) & 7;
  const int z = bid >> 9;           // K-split quarter: 49 = 13+12+12+12
  const int kt0 = (z == 0) ? 0 : (13 + (z - 1) * 12);
  const int ktn = (z == 0) ? 13 : 12;

  const int t = threadIdx.x;
  const int lane = t & 63;
  const int wv = t >> 6;
  const int r = lane & 15;
  const int q = lane >> 4;
  const int wm = wv >> 1, wn = wv & 1;  // 2x2 wave grid over 128x128 tile

  // staging: wave wv, instr p covers rows [wv*32 + p*8, +8); lane -> (rr, cs)
  const int rr = lane >> 3;         // row within 8-row group
  const int k8 = (lane & 7) ^ rr;   // swizzled global chunk for this slot
  const short* Aw = Abf + (size_t)(mt * 128 + wv * 32 + rr) * K_DIM + k8 * 8 + kt0 * 64;
  const short* Bw = Bbf + (size_t)(nt * 128 + wv * 32 + rr) * K_DIM + k8 * 8 + kt0 * 64;
  char* AsB = (char*)As + wv * 4096;
  char* BsB = (char*)Bs + wv * 4096;

  f32x4 acc[4][4];
#pragma unroll
  for (int i = 0; i < 4; ++i)
#pragma unroll
    for (int j = 0; j < 4; ++j) acc[i][j] = (f32x4)0.0f;

  for (int kt = 0; kt < ktn; ++kt) {
    __syncthreads();  // prev iteration's LDS reads done
#pragma unroll
    for (int p = 0; p < 4; ++p) {
      async16(Aw + (size_t)p * 8 * K_DIM + kt * 64, AsB + p * 1024);
      async16(Bw + (size_t)p * 8 * K_DIM + kt * 64, BsB + p * 1024);
    }
    __syncthreads();  // vmcnt(0) drain: DMA complete across all waves

#pragma unroll
    for (int ks = 0; ks < 2; ++ks) {
      const int xo = ((ks * 4 + q) ^ (r & 7)) * 16;
      short8v a[4], b[4];
#pragma unroll
      for (int i = 0; i < 4; ++i)
        a[i] = *(const short8v*)((const char*)As + (64 * wm + 16 * i + r) * 128 + xo);
#pragma unroll
      for (int j = 0; j < 4; ++j)
        b[j] = *(const short8v*)((const char*)Bs + (64 * wn + 16 * j + r) * 128 + xo);
#pragma unroll
      for (int i = 0; i < 4; ++i)
#pragma unroll
        for (int j = 0; j < 4; ++j)
          acc[i][j] = __builtin_amdgcn_mfma_f32_16x16x32_bf16(a[i], b[j],
                                                              acc[i][j], 0, 0, 0);
    }
  }

  // epilogue: out[b, n] += sum_c acc * W_d[n, c]; C/D: col=lane&15, row=q*4+reg
  const int b_idx = mt >> 1;
  const int c0 = (mt & 1) * 128;
  const int n0 = nt * 128;
#pragma unroll
  for (int j = 0; j < 4; ++j) {
    const int n_g = n0 + 64 * wn + 16 * j + r;
    float p = 0.0f;
#pragma unroll
    for (int i = 0; i < 4; ++i) {
      const int c_l = c0 + 64 * wm + 16 * i + 4 * q;
      const float4 wd = *(const float4*)(Wd + (size_t)n_g * C_DIM + c_l);
      p += acc[i][j].x * wd.x + acc[i][j].y * wd.y + acc[i][j].z * wd.z +
           acc[i][j].w * wd.w;
    }
    p += __shfl_xor(p, 16, 64);
    p += __shfl_xor(p, 32, 64);
    if (q == 0) atomicAdd(&out[(size_t)b_idx * N_DIM + n_g], p);
  }
}

extern "C" void kernel_launch(void* const* d_in, const int* in_sizes, int n_in,
                              void* d_out, int out_size, void* d_ws, size_t ws_size,
                              hipStream_t stream) {
  const float* x = (const float*)d_in[0];
  const float* Ws = (const float*)d_in[1];
  const float* Wd = (const float*)d_in[2];
  const float* Wb = (const float*)d_in[3];
  float* out = (float*)d_out;
  short* xbf = (short*)d_ws;  // [X_ELEMS] bf16 x, then [WS_ELEMS] bf16 W_s

  convert_bf16_bias<<<dim3(CVBLK + 128), dim3(256), 0, stream>>>(x, Ws, Wb, xbf, out);
  gemm_fused<<<dim3(64 * 8 * 4), dim3(256), 0, stream>>>(xbf, xbf + X_ELEMS, Wd, out);
}

// Round 6
// 209.566 us; speedup vs baseline: 2.4521x; 1.0115x over previous
//
#include <hip/hip_runtime.h>
#include <stdint.h>

// out[b,n] = sum_{c,hw} x[b,c,hw]*W_s[n,hw]*W_d[n,c] + W_b[n]
// GEMM: A = x (M=8192, K=3136), B = W_s (N=1024, K=3136), fused c-contraction.
// R5: 256x128 tile, 512 threads (8 waves, 4x2), BK=64, split-K x2 (grid 512 =
//     2 blocks/CU, 16 waves/CU). DMA bytes/MAC -25% vs 128x128 (suspected
//     global->LDS ingest bound: 28.6 B/cyc/CU at R4). A-tile = one image.

#define K_DIM 3136
#define N_DIM 1024
#define C_DIM 256
#define B_DIM 32
#define M_DIM 8192
#define X_ELEMS (M_DIM * K_DIM)   // 25690112
#define WS_ELEMS (N_DIM * K_DIM)  // 3211264

typedef __attribute__((ext_vector_type(8))) short short8v;  // 8 bf16
typedef __attribute__((ext_vector_type(4))) float f32x4;

__device__ __forceinline__ short f2bf(float f) {
  union { float f; unsigned u; } v; v.f = f;
  unsigned r = v.u + 0x7FFFu + ((v.u >> 16) & 1u);
  return (short)(r >> 16);
}

// 16B-per-lane async global->LDS. LDS dest = wave-uniform base + lane*16.
__device__ __forceinline__ void async16(const void* g, void* l) {
  __builtin_amdgcn_global_load_lds(
      (const __attribute__((address_space(1))) unsigned int*)g,
      (__attribute__((address_space(3))) unsigned int*)l, 16, 0, 0);
}

// fp32 -> bf16 for x and W_s, plus bias broadcast into out (last 128 blocks).
#define XBLK (X_ELEMS / 2048)                 // 12544
#define CVBLK ((X_ELEMS + WS_ELEMS) / 2048)   // 14112
__global__ __launch_bounds__(256) void convert_bf16_bias(
    const float* __restrict__ x, const float* __restrict__ Ws,
    const float* __restrict__ Wb, short* __restrict__ dst,
    float* __restrict__ out) {
  int bid = blockIdx.x;
  if (bid >= CVBLK) {  // bias: 32768 out elems / 256 = 128 blocks
    int i = (bid - CVBLK) * 256 + threadIdx.x;
    out[i] = Wb[i & (N_DIM - 1)];
    return;
  }
  const float* src;
  short* d;
  size_t base;
  if (bid < XBLK) {
    src = x; d = dst; base = (size_t)bid * 2048;
  } else {
    src = Ws; d = dst + X_ELEMS; base = (size_t)(bid - XBLK) * 2048;
  }
  size_t i = base + threadIdx.x * 8;
  f32x4 v0 = __builtin_nontemporal_load((const f32x4*)(src + i));
  f32x4 v1 = __builtin_nontemporal_load((const f32x4*)(src + i) + 1);
  short8v s;
  s[0] = f2bf(v0.x); s[1] = f2bf(v0.y); s[2] = f2bf(v0.z); s[3] = f2bf(v0.w);
  s[4] = f2bf(v1.x); s[5] = f2bf(v1.y); s[6] = f2bf(v1.z); s[7] = f2bf(v1.w);
  *(short8v*)(d + i) = s;
}

// LDS: rows of 8 chunks (chunk = 8 bf16 = 16 B), unpadded (DMA dest).
// slot(row, cs) holds global chunk k8 = cs ^ (row&7); frag reads XOR back ->
// conflict-free (verified R1/R3: SQ_LDS_BANK_CONFLICT = 0).
__global__ __launch_bounds__(512, 4) void gemm_fused(
    const short* __restrict__ Abf, const short* __restrict__ Bbf,
    const float* __restrict__ Wd, float* __restrict__ out) {
  __shared__ __align__(16) short As[256 * 64];  // 32 KB
  __shared__ __align__(16) short Bs[128 * 64];  // 16 KB

  const int bid = blockIdx.x;
  const int mt = bid & 31;          // bid%8 == mt%8 -> A-tile pinned to XCD
  const int nt = (bid >> 5) & 7;
  const int z = bid >> 8;           // K-split half: 49 = 25 + 24
  const int kt0 = z * 25;
  const int ktn = z ? 24 : 25;

  const int t = threadIdx.x;
  const int lane = t & 63;
  const int wv = t >> 6;            // 0..7
  const int r = lane & 15;
  const int q = lane >> 4;
  const int wm = wv >> 1, wn = wv & 1;  // 4x2 wave grid over 256x128 tile

  // staging: lane -> (rr, cs); A: wave covers rows [wv*32, +32) via p=0..3,
  // B: rows [wv*16, +16) via p=0..1. Each async16 instr = 8 rows x 8 chunks.
  const int rr = lane >> 3;
  const int k8 = (lane & 7) ^ rr;   // swizzled global chunk for this slot
  const short* Aw = Abf + (size_t)(mt * 256 + wv * 32 + rr) * K_DIM + k8 * 8 + kt0 * 64;
  const short* Bw = Bbf + (size_t)(nt * 128 + wv * 16 + rr) * K_DIM + k8 * 8 + kt0 * 64;
  char* AsB = (char*)As + wv * 4096;
  char* BsB = (char*)Bs + wv * 2048;

  f32x4 acc[4][4];
#pragma unroll
  for (int i = 0; i < 4; ++i)
#pragma unroll
    for (int j = 0; j < 4; ++j) acc[i][j] = (f32x4)0.0f;

  for (int kt = 0; kt < ktn; ++kt) {
    __syncthreads();  // prev iteration's LDS reads done
#pragma unroll
    for (int p = 0; p < 4; ++p)
      async16(Aw + (size_t)p * 8 * K_DIM + kt * 64, AsB + p * 1024);
#pragma unroll
    for (int p = 0; p < 2; ++p)
      async16(Bw + (size_t)p * 8 * K_DIM + kt * 64, BsB + p * 1024);
    __syncthreads();  // vmcnt(0) drain: DMA complete across all waves

#pragma unroll
    for (int ks = 0; ks < 2; ++ks) {
      const int xo = ((ks * 4 + q) ^ (r & 7)) * 16;
      short8v a[4], b[4];
#pragma unroll
      for (int i = 0; i < 4; ++i)
        a[i] = *(const short8v*)((const char*)As + (64 * wm + 16 * i + r) * 128 + xo);
#pragma unroll
      for (int j = 0; j < 4; ++j)
        b[j] = *(const short8v*)((const char*)Bs + (64 * wn + 16 * j + r) * 128 + xo);
#pragma unroll
      for (int i = 0; i < 4; ++i)
#pragma unroll
        for (int j = 0; j < 4; ++j)
          acc[i][j] = __builtin_amdgcn_mfma_f32_16x16x32_bf16(a[i], b[j],
                                                              acc[i][j], 0, 0, 0);
    }
  }

  // epilogue: out[mt, n] += sum_c acc * W_d[n, c]; A-tile = image mt, c = row.
  // C/D frag layout: col = lane&15 (n), row = q*4 + reg (c).
#pragma unroll
  for (int j = 0; j < 4; ++j) {
    const int n_g = nt * 128 + 64 * wn + 16 * j + r;
    float p = 0.0f;
#pragma unroll
    for (int i = 0; i < 4; ++i) {
      const int c_l = 64 * wm + 16 * i + 4 * q;
      const float4 wd = *(const float4*)(Wd + (size_t)n_g * C_DIM + c_l);
      p += acc[i][j].x * wd.x + acc[i][j].y * wd.y + acc[i][j].z * wd.z +
           acc[i][j].w * wd.w;
    }
    p += __shfl_xor(p, 16, 64);
    p += __shfl_xor(p, 32, 64);
    if (q == 0) atomicAdd(&out[(size_t)mt * N_DIM + n_g], p);
  }
}

extern "C" void kernel_launch(void* const* d_in, const int* in_sizes, int n_in,
                              void* d_out, int out_size, void* d_ws, size_t ws_size,
                              hipStream_t stream) {
  const float* x = (const float*)d_in[0];
  const float* Ws = (const float*)d_in[1];
  const float* Wd = (const float*)d_in[2];
  const float* Wb = (const float*)d_in[3];
  float* out = (float*)d_out;
  short* xbf = (short*)d_ws;  // [X_ELEMS] bf16 x, then [WS_ELEMS] bf16 W_s

  convert_bf16_bias<<<dim3(CVBLK + 128), dim3(256), 0, stream>>>(x, Ws, Wb, xbf, out);
  gemm_fused<<<dim3(32 * 8 * 2), dim3(512), 0, stream>>>(xbf, xbf + X_ELEMS, Wd, out);
}